// Round 16
// baseline (753.170 us; speedup 1.0000x reference)
//
#include <hip/hip_runtime.h>

#define Bn 128
#define Wn 64

typedef _Float16 h2 __attribute__((ext_vector_type(2)));

// ---- device state ----
__device__ unsigned g_sf[256];                // score partials posted, value t+1
__device__ unsigned g_stf4[4][256];           // state slice posted per chain, value t+1
__device__ unsigned g_scp[256][2][256];       // [g][t&1][c*64+w] score partials (f32 bits)
__device__ unsigned g_stp[256][2][128];       // [g][t&1][c*32 + (h:0..15|c:16..31)] f16 pairs
__device__ unsigned g_ep16[Bn * Wn * 128];    // eproj f16 pairs [b][w][128]
__device__ float4 g_encfc[Bn * Wn];           // fc_w[:, :256] @ enc
__device__ float4 g_encfcf[Bn * Wn];          // fcf_w[:, 256:] @ enc
__device__ uint4 g_w1pk[8 * 32 * 64];         // [m][e_loc][ku]  w1 rows, full K (pairs)
__device__ uint4 g_whpk[8 * 128 * 32];        // [m][rq][i]      whh rows (q*32+dl), h-K

__device__ __forceinline__ float ftanh(float x) {
  float p = __builtin_exp2f(x * 2.885390081777927f);
  return 1.0f - 2.0f * __builtin_amdgcn_rcpf(p + 1.0f);
}
__device__ __forceinline__ float fsigm(float x) {
  float p = __builtin_exp2f(-x * 1.4426950408889634f);
  return __builtin_amdgcn_rcpf(1.0f + p);
}
__device__ __forceinline__ float dot4(float4 a, float4 b) {
  return a.x * b.x + a.y * b.y + a.z * b.z + a.w * b.w;
}
__device__ __forceinline__ float fd2(unsigned w, unsigned h, float acc) {
  h2 a = __builtin_bit_cast(h2, w), b = __builtin_bit_cast(h2, h);
#if __has_builtin(__builtin_amdgcn_fdot2)
  return __builtin_amdgcn_fdot2(a, b, acc, false);
#else
  return acc + (float)a.x * (float)b.x + (float)a.y * (float)b.y;
#endif
}
__device__ __forceinline__ float fd2x4u(uint4 w, uint4 h, float acc) {
  acc = fd2(w.x, h.x, acc);
  acc = fd2(w.y, h.y, acc);
  acc = fd2(w.z, h.z, acc);
  acc = fd2(w.w, h.w, acc);
  return acc;
}
__device__ __forceinline__ unsigned pk(float a, float b) {
  h2 h = {(_Float16)a, (_Float16)b};
  return __builtin_bit_cast(unsigned, h);
}
__device__ __forceinline__ void ast(unsigned* p, unsigned v) {
  __hip_atomic_store(p, v, __ATOMIC_RELAXED, __HIP_MEMORY_SCOPE_AGENT);
}
__device__ __forceinline__ unsigned ald(unsigned* p) {
  return __hip_atomic_load(p, __ATOMIC_RELAXED, __HIP_MEMORY_SCOPE_AGENT);
}
__device__ __forceinline__ float aldf(unsigned* p) {
  return __builtin_bit_cast(float, ald(p));
}

// state phys layout: logical uint4 L (0..63) of chain c -> c*68 + (L>>4)*17 + (L&15)
#define STPHYS(c, L) ((c) * 68 + ((L) >> 4) * 17 + ((L) & 15))

// ---------------- reset ----------------
__global__ void reset_kernel(float* out) {
  int t = threadIdx.x;
  if (t < 256) {
    g_sf[t] = 0u;
    g_stf4[0][t] = 0u; g_stf4[1][t] = 0u; g_stf4[2][t] = 0u; g_stf4[3][t] = 0u;
  }
  if (t < 512) out[t] = 0.f;
}

// ---------------- pack weights into member slices ----------------
__global__ __launch_bounds__(256) void pack_kernel(const float* __restrict__ w1,
                                                   const float* __restrict__ w_hh) {
  int idx = blockIdx.x * 256 + threadIdx.x;  // 49152 tasks
  const float* src;
  uint4* dst;
  if (idx < 16384) {                         // w1: m, e_loc, ku
    int m = idx >> 11, e_loc = (idx >> 6) & 31, ku = idx & 63;
    int e = m * 32 + e_loc;
    src = w1 + (size_t)e * 768 + 8 * ku;     // cols 0..511 = [W1h|W1c]
    dst = g_w1pk + idx;
  } else {                                   // whh: m, rq=q*32+dl, i
    int j = idx - 16384;
    int m = j >> 12, rq = (j >> 5) & 127, i = j & 31;
    int q = rq >> 5, dl = rq & 31;
    int R = q * 256 + m * 32 + dl;
    src = w_hh + (size_t)R * 256 + 8 * i;
    dst = g_whpk + j;
  }
  uint4 o;
  o.x = pk(src[0], src[1]); o.y = pk(src[2], src[3]);
  o.z = pk(src[4], src[5]); o.w = pk(src[6], src[7]);
  *dst = o;
}

// ---------------- eproj: b1 + W1e @ enc -> f16 pairs ----------------
__global__ __launch_bounds__(256) void eproj_kernel(const float* __restrict__ enc,
                                                    const float* __restrict__ w1,
                                                    const float* __restrict__ b1) {
  __shared__ __align__(16) float4 encs[16][64];
  __shared__ float accs[16][256];
  const int m0 = blockIdx.x * 16;
  const int tid = threadIdx.x;
  const float4* eg = (const float4*)(enc + (size_t)m0 * 256);
#pragma unroll
  for (int i = 0; i < 4; i++) {
    int idx = tid + 256 * i;
    encs[idx >> 6][idx & 63] = eg[idx];
  }
  __syncthreads();
  const int e = tid;
  float acc[16];
#pragma unroll
  for (int i = 0; i < 16; i++) acc[i] = 0.f;
  const float4* wrow = (const float4*)(w1 + e * 768 + 512);
  for (int k4 = 0; k4 < 64; k4++) {
    float4 wv = wrow[k4];
#pragma unroll
    for (int i = 0; i < 16; i++) acc[i] += dot4(wv, encs[i][k4]);
  }
  float bb = b1[e];
#pragma unroll
  for (int i = 0; i < 16; i++) accs[i][e] = acc[i] + bb;
  __syncthreads();
#pragma unroll
  for (int r = 0; r < 8; r++) {
    int idx = r * 256 + tid;
    int i = idx >> 7, jp = idx & 127;
    g_ep16[(size_t)(m0 + i) * 128 + jp] = pk(accs[i][2 * jp], accs[i][2 * jp + 1]);
  }
}

// ---------------- ENCFC / ENCFCF precompute ----------------
__global__ __launch_bounds__(256) void encfc_kernel(const float* __restrict__ enc,
                                                    const float* __restrict__ fc_w,
                                                    const float* __restrict__ fcf_w) {
  __shared__ __align__(16) float4 encs[16][64];
  const int m0 = blockIdx.x * 16;
  const int tid = threadIdx.x;
  const float4* eg = (const float4*)(enc + (size_t)m0 * 256);
#pragma unroll
  for (int i = 0; i < 4; i++) {
    int idx = tid + 256 * i;
    encs[idx >> 6][idx & 63] = eg[idx];
  }
  __syncthreads();
  if (tid < 128) {
    const int r = tid >> 3, o = tid & 7;
    const float* wr = (o < 4) ? (fc_w + o * 260) : (fcf_w + (o - 4) * 512 + 256);
    const float4* w4 = (const float4*)wr;
    float a = 0.f;
#pragma unroll 8
    for (int k = 0; k < 64; k++) a += dot4(w4[k], encs[r][k]);
    if (o < 4) ((float*)&g_encfc[m0 + r])[o] = a;
    else ((float*)&g_encfcf[m0 + r])[o - 4] = a;
  }
}

// -------- decoder: 8-CU LDS-parked group; fused C+D (4 barriers/step) --------
__global__ __launch_bounds__(512, 1) void decoder_kernel(
    const float* __restrict__ yhist, const float* __restrict__ w2,
    const float* __restrict__ w_ih, const float* __restrict__ b_ih,
    const float* __restrict__ b_hh,
    const float* __restrict__ fc_w, const float* __restrict__ fc_b,
    const float* __restrict__ fcf_w, const float* __restrict__ fcf_b,
    float* __restrict__ out) {
  __shared__ __align__(16) uint4 w1l[32 * 65];    // 33.3 KB [e_loc][ku] pad65
  __shared__ __align__(16) uint4 whl[128 * 33];   // 67.6 KB [rq][i] pad33
  __shared__ __align__(16) uint4 ep_t[4 * 257];   // 16.4 KB [u4][c*64+w] pad257
  __shared__ __align__(16) uint4 st4[4 * 68];     //  4.3 KB state, phys STPHYS
  __shared__ __align__(16) float4 encfc_l[256];
  __shared__ __align__(16) float4 yh_l[256];
  __shared__ __align__(16) float4 wihl[132];      // [q*33+dl]
  __shared__ float biasl[132];                    // [q*33+dl]
  __shared__ float ag_l[4 * 133];                 // [c*133 + q*32+dl]
  __shared__ float hcp_l[4 * 36];
  __shared__ float w2_l[32];
  __shared__ float scp_l[256];                    // own score partials
  __shared__ float sc_part[7 * 256];              // one region per partner wave
  __shared__ float cl[132];                       // [c*33 + dl]
  __shared__ float fcy_l[16];
  __shared__ float fcb_l[4];

  const int g = blockIdx.x, t = threadIdx.x;
  const int m = (g >> 3) & 7;
  const int gx = g - 8 * m;
  const int G = (g & 7) * 4 + (g >> 6);
  const int cbase = 4 * G;
  const int l = t & 63, wv = t >> 6;
  const int e_loc = t >> 4, ks = t & 15;   // A1 mapping
  const int row = t >> 2, kq2 = t & 3;     // A2 mapping

  unsigned* st32 = (unsigned*)st4;

  // ---- LDS init ----
#pragma unroll
  for (int j = 0; j < 4; j++) {
    int f = t + 512 * j;
    w1l[(f >> 6) * 65 + (f & 63)] = g_w1pk[m * 2048 + f];
  }
#pragma unroll
  for (int j = 0; j < 8; j++) {
    int f = t + 512 * j;
    whl[(f >> 5) * 33 + (f & 31)] = g_whpk[m * 4096 + f];
  }
#pragma unroll
  for (int j = 0; j < 2; j++) {
    int f = t + 512 * j;
    int u = f >> 8, cw = f & 255, c = cw >> 6, w = cw & 63;
    ep_t[u * 257 + cw] =
        ((const uint4*)(g_ep16 + ((size_t)((cbase + c) * 64 + w)) * 128))[m * 4 + u];
  }
  if (t < 272) st4[t] = (uint4){0u, 0u, 0u, 0u};
  if (t < 256) {
    int c = t >> 6, w = t & 63;
    encfc_l[t] = g_encfc[(cbase + c) * 64 + w];
    yh_l[t] = ((const float4*)yhist)[(cbase + c) * 64 + w];
  }
  if (t < 128) {
    int q = t >> 5, dl = t & 31;
    int R = q * 256 + m * 32 + dl;
    wihl[q * 33 + dl] = *(const float4*)(w_ih + (size_t)R * 4);
    biasl[q * 33 + dl] = b_ih[R] + b_hh[R];
  }
  if (t < 132) cl[t] = 0.f;
  if (t < 32) w2_l[t] = w2[m * 32 + t];
  if (t < 16) fcy_l[t] = fc_w[(t >> 2) * 260 + 256 + (t & 3)];
  if (t < 4) fcb_l[t] = fc_b[t];
  __syncthreads();

  float attw = 0.f;
  for (int tstep = 0; tstep < Wn; tstep++) {
    const int tb = tstep & 1;
    const unsigned want = (unsigned)(tstep + 1);
    // ---- A1: hcp for own 32 e-rows, 4 chains, full K=512 ----
    {
      float a0 = 0.f, a1 = 0.f, a2 = 0.f, a3 = 0.f;
      const uint4* wrow = &w1l[e_loc * 65 + 4 * ks];
#pragma unroll
      for (int j = 0; j < 4; j++) {
        uint4 wvv = wrow[j];
        int ku = 4 * ks + j;
        int ph = (ku >> 4) * 17 + (ku & 15);
        a0 = fd2x4u(wvv, st4[ph], a0);
        a1 = fd2x4u(wvv, st4[68 + ph], a1);
        a2 = fd2x4u(wvv, st4[136 + ph], a2);
        a3 = fd2x4u(wvv, st4[204 + ph], a3);
      }
#pragma unroll
      for (int dd = 1; dd < 16; dd <<= 1) {
        a0 += __shfl_xor(a0, dd, 64);
        a1 += __shfl_xor(a1, dd, 64);
        a2 += __shfl_xor(a2, dd, 64);
        a3 += __shfl_xor(a3, dd, 64);
      }
      if (ks == 0) {
        hcp_l[e_loc] = a0;
        hcp_l[36 + e_loc] = a1;
        hcp_l[72 + e_loc] = a2;
        hcp_l[108 + e_loc] = a3;
      }
    }
    __syncthreads();  // B1
    // ---- B: score partials over own 32 e's ----
    {
      const int cB = t >> 7, wB = (t & 127) >> 1, halfB = t & 1;
      float s = 0.f;
#pragma unroll
      for (int j = 0; j < 2; j++) {
        int u = 2 * halfB + j;
        uint4 uu = ep_t[u * 257 + cB * 64 + wB];
        unsigned um[4] = {uu.x, uu.y, uu.z, uu.w};
#pragma unroll
        for (int ui = 0; ui < 4; ui++) {
          int e0 = 2 * (4 * u + ui);
          h2 aa = __builtin_bit_cast(h2, um[ui]);
          s += w2_l[e0] * ftanh((float)aa.x + hcp_l[cB * 36 + e0]);
          s += w2_l[e0 + 1] * ftanh((float)aa.y + hcp_l[cB * 36 + e0 + 1]);
        }
      }
      s += __shfl_xor(s, 1, 64);
      if (halfB == 0) scp_l[cB * 64 + wB] = s;
    }
    __syncthreads();  // B2
    // ---- post scores (wave 0) then everyone does A2; waves 1-7 gather 1 partner each ----
    if (wv == 0) {
      unsigned* dst = &g_scp[g][tb][4 * l];
      ast(dst + 0, __builtin_bit_cast(unsigned, scp_l[4 * l + 0]));
      ast(dst + 1, __builtin_bit_cast(unsigned, scp_l[4 * l + 1]));
      ast(dst + 2, __builtin_bit_cast(unsigned, scp_l[4 * l + 2]));
      ast(dst + 3, __builtin_bit_cast(unsigned, scp_l[4 * l + 3]));
      asm volatile("s_waitcnt vmcnt(0)" ::: "memory");
      if (l == 0) ast(&g_sf[g], want);
    }
    // ---- A2: gate h-dots; thread=(row,kq2) computes 4 chains from ONE whl read ----
    {
      float b0 = 0.f, b1 = 0.f, b2 = 0.f, b3 = 0.f;
      const uint4* wr = &whl[row * 33 + 8 * kq2];
#pragma unroll
      for (int j = 0; j < 8; j++) {
        uint4 wvv = wr[j];
        int i = 8 * kq2 + j;  // logical uint4 0..31 (h region)
        int ph = (i >> 4) * 17 + (i & 15);
        b0 = fd2x4u(wvv, st4[ph], b0);
        b1 = fd2x4u(wvv, st4[68 + ph], b1);
        b2 = fd2x4u(wvv, st4[136 + ph], b2);
        b3 = fd2x4u(wvv, st4[204 + ph], b3);
      }
#pragma unroll
      for (int dd = 1; dd < 4; dd <<= 1) {
        b0 += __shfl_xor(b0, dd, 64);
        b1 += __shfl_xor(b1, dd, 64);
        b2 += __shfl_xor(b2, dd, 64);
        b3 += __shfl_xor(b3, dd, 64);
      }
      if (kq2 == 0) {
        ag_l[row] = b0;
        ag_l[133 + row] = b1;
        ag_l[266 + row] = b2;
        ag_l[399 + row] = b3;
      }
    }
    // ---- gather scores: wave wv (1..7) handles partner (m+wv)&7 ----
    if (wv >= 1) {
      const int mo = (m + wv) & 7;
      if (l == 0) {
        unsigned* fp = &g_sf[gx + 8 * mo];
        while (ald(fp) < want) __builtin_amdgcn_s_sleep(1);
      }
      asm volatile("" ::: "memory");
      unsigned* sp = &g_scp[gx + 8 * mo][tb][4 * l];
      float* dst = &sc_part[(wv - 1) * 256 + 4 * l];
      dst[0] = aldf(sp + 0);
      dst[1] = aldf(sp + 1);
      dst[2] = aldf(sp + 2);
      dst[3] = aldf(sp + 3);
    }
    __syncthreads();  // B3
    // ---- fused C+D: waves 0-3 = chain wv (softmax->ytilde->gates->LSTM->post);
    //                 waves 4-7 = gather partner states ----
    if (wv < 4) {
      const int c = wv;
      float sc = scp_l[c * 64 + l];
#pragma unroll
      for (int k = 0; k < 7; k++) sc += sc_part[k * 256 + c * 64 + l];
      float mm = sc;
#pragma unroll
      for (int dd = 32; dd; dd >>= 1) mm = fmaxf(mm, __shfl_xor(mm, dd, 64));
      float pr = __builtin_exp2f((sc - mm) * 1.4426950408889634f);
      float su = pr;
#pragma unroll
      for (int dd = 32; dd; dd >>= 1) su += __shfl_xor(su, dd, 64);
      attw = pr * __builtin_amdgcn_rcpf(su);
      float4 ef = encfc_l[c * 64 + l];
      float rx = attw * ef.x, ry = attw * ef.y, rz = attw * ef.z, rw = attw * ef.w;
#pragma unroll
      for (int dd = 32; dd; dd >>= 1) {
        rx += __shfl_xor(rx, dd, 64);
        ry += __shfl_xor(ry, dd, 64);
        rz += __shfl_xor(rz, dd, 64);
        rw += __shfl_xor(rw, dd, 64);
      }
      // every lane now holds the reduced sums -> yt4 in-register, no LDS round-trip
      float4 yv = yh_l[c * 64 + tstep];
      float4 yt;
      yt.x = rx + fcb_l[0] + fcy_l[0] * yv.x + fcy_l[1] * yv.y + fcy_l[2] * yv.z + fcy_l[3] * yv.w;
      yt.y = ry + fcb_l[1] + fcy_l[4] * yv.x + fcy_l[5] * yv.y + fcy_l[6] * yv.z + fcy_l[7] * yv.w;
      yt.z = rz + fcb_l[2] + fcy_l[8] * yv.x + fcy_l[9] * yv.y + fcy_l[10] * yv.z + fcy_l[11] * yv.w;
      yt.w = rw + fcb_l[3] + fcy_l[12] * yv.x + fcy_l[13] * yv.y + fcy_l[14] * yv.z + fcy_l[15] * yv.w;
      // gates + LSTM for chain c (lanes 0-15, d-pairs)
      if (l < 16) {
        const int pp = l;
        const int d0 = 2 * pp, d1 = d0 + 1;
#define GV(q, d) (ag_l[c * 133 + (q) * 32 + (d)] + biasl[(q) * 33 + (d)] + dot4(wihl[(q) * 33 + (d)], yt))
        float i0 = fsigm(GV(0, d0)), f0 = fsigm(GV(1, d0));
        float G0 = ftanh(GV(2, d0)), o0 = fsigm(GV(3, d0));
        float i1 = fsigm(GV(0, d1)), f1 = fsigm(GV(1, d1));
        float G1 = ftanh(GV(2, d1)), o1 = fsigm(GV(3, d1));
#undef GV
        float cn0 = f0 * cl[c * 33 + d0] + i0 * G0;
        float cn1 = f1 * cl[c * 33 + d1] + i1 * G1;
        float hn0 = o0 * ftanh(cn0), hn1 = o1 * ftanh(cn1);
        cl[c * 33 + d0] = cn0; cl[c * 33 + d1] = cn1;
        unsigned hp = pk(hn0, hn1), cp = pk(cn0, cn1);
        int Lh = 4 * m + (pp >> 2), Lc = 32 + 4 * m + (pp >> 2);
        st32[4 * STPHYS(c, Lh) + (pp & 3)] = hp;
        st32[4 * STPHYS(c, Lc) + (pp & 3)] = cp;
        if (tstep < 63) {
          ast(&g_stp[g][tb][c * 32 + pp], hp);
          ast(&g_stp[g][tb][c * 32 + 16 + pp], cp);
        }
      }
      if (tstep < 63) {
        asm volatile("s_waitcnt vmcnt(0)" ::: "memory");
        if (l == 0) ast(&g_stf4[c][g], want);
      }
    } else if (tstep < 63) {
      // waves 4-7: partner state gather; wave4:{1,5} wave5:{2,6} wave6:{3,7} wave7:{4}
      for (int kk = wv - 3; kk < 8; kk += 4) {
        const int mo = (m + kk) & 7;
        if (l == 0) {
          while (ald(&g_stf4[0][gx + 8 * mo]) < want) __builtin_amdgcn_s_sleep(1);
          while (ald(&g_stf4[1][gx + 8 * mo]) < want) __builtin_amdgcn_s_sleep(1);
          while (ald(&g_stf4[2][gx + 8 * mo]) < want) __builtin_amdgcn_s_sleep(1);
          while (ald(&g_stf4[3][gx + 8 * mo]) < want) __builtin_amdgcn_s_sleep(1);
        }
        asm volatile("" ::: "memory");
        if (l < 32) {
          unsigned* sp = &g_stp[gx + 8 * mo][tb][4 * l];
#pragma unroll
          for (int k2 = 0; k2 < 4; k2++) {
            unsigned v = ald(sp + k2);
            int i = 4 * l + k2;
            int c = i >> 5, r = i & 31, pp = r & 15, isC = r >> 4;
            int L = isC * 32 + 4 * mo + (pp >> 2);
            st32[4 * STPHYS(c, L) + (pp & 3)] = v;
          }
        }
      }
    }
    __syncthreads();  // B4
  }

  // ---- final: out[b,f] += fcf_h (own d-slice) + [m==0](attn.ENCFCF + fcf_b) ----
  if (wv < 4) {
    const int c = wv, b = cbase + c;
    const int pp = l & 15, f = l >> 4;
    int Lh = 4 * m + (pp >> 2);
    h2 hh = __builtin_bit_cast(h2, st32[4 * STPHYS(c, Lh) + (pp & 3)]);
    const int d0 = m * 32 + 2 * pp;
    float v = fcf_w[f * 512 + d0] * (float)hh.x + fcf_w[f * 512 + d0 + 1] * (float)hh.y;
#pragma unroll
    for (int dd = 1; dd < 16; dd <<= 1) v += __shfl_xor(v, dd, 64);
    if (pp == 0) atomicAdd(out + b * 4 + f, v);
    if (m == 0) {
      float4 fv = g_encfcf[b * 64 + l];
      float vx = attw * fv.x, vy = attw * fv.y, vz = attw * fv.z, vw = attw * fv.w;
#pragma unroll
      for (int dd = 32; dd; dd >>= 1) {
        vx += __shfl_xor(vx, dd, 64);
        vy += __shfl_xor(vy, dd, 64);
        vz += __shfl_xor(vz, dd, 64);
        vw += __shfl_xor(vw, dd, 64);
      }
      if (l == 0) {
        atomicAdd(out + b * 4 + 0, vx + fcf_b[0]);
        atomicAdd(out + b * 4 + 1, vy + fcf_b[1]);
        atomicAdd(out + b * 4 + 2, vz + fcf_b[2]);
        atomicAdd(out + b * 4 + 3, vw + fcf_b[3]);
      }
    }
  }
}

extern "C" void kernel_launch(void* const* d_in, const int* in_sizes, int n_in,
                              void* d_out, int out_size, void* d_ws, size_t ws_size,
                              hipStream_t stream) {
  (void)in_sizes; (void)n_in; (void)d_ws; (void)ws_size; (void)out_size;
  const float* enc   = (const float*)d_in[0];
  const float* yhist = (const float*)d_in[1];
  const float* w1    = (const float*)d_in[2];
  const float* b1    = (const float*)d_in[3];
  const float* w2    = (const float*)d_in[4];
  // d_in[5] = attn_b2: softmax-invariant -> unused
  const float* w_ih  = (const float*)d_in[6];
  const float* w_hh  = (const float*)d_in[7];
  const float* b_ih  = (const float*)d_in[8];
  const float* b_hh  = (const float*)d_in[9];
  const float* fc_w  = (const float*)d_in[10];
  const float* fc_b  = (const float*)d_in[11];
  const float* fcf_w = (const float*)d_in[12];
  const float* fcf_b = (const float*)d_in[13];
  float* out = (float*)d_out;

  reset_kernel<<<dim3(1), dim3(512), 0, stream>>>(out);
  pack_kernel<<<dim3(192), dim3(256), 0, stream>>>(w1, w_hh);
  eproj_kernel<<<dim3(512), dim3(256), 0, stream>>>(enc, w1, b1);
  encfc_kernel<<<dim3(512), dim3(256), 0, stream>>>(enc, fc_w, fcf_w);
  decoder_kernel<<<dim3(256), dim3(512), 0, stream>>>(yhist, w2, w_ih, b_ih, b_hh,
                                                      fc_w, fc_b, fcf_w, fcf_b, out);
}

// Round 17
// 703.227 us; speedup vs baseline: 1.0710x; 1.0710x over previous
//
#include <hip/hip_runtime.h>

#define Bn 128
#define Wn 64

typedef _Float16 h2 __attribute__((ext_vector_type(2)));

// ---- device state ----
__device__ unsigned g_sf[256];                // score partials posted, value t+1
__device__ unsigned g_stf[256];               // state slice posted, value t+1
__device__ unsigned g_scp[256][2][256];       // [g][t&1][c*64+w] score partials (f32 bits)
__device__ unsigned g_stp[256][2][128];       // [g][t&1][c*32 + (h:0..15|c:16..31)] f16 pairs
__device__ unsigned g_ep16[Bn * Wn * 128];    // eproj f16 pairs [b][w][128]
__device__ float4 g_encfc[Bn * Wn];           // fc_w[:, :256] @ enc
__device__ float4 g_encfcf[Bn * Wn];          // fcf_w[:, 256:] @ enc
__device__ uint4 g_w1pk[8 * 32 * 64];         // [m][e_loc][ku]  w1 rows, full K (pairs)
__device__ uint4 g_whpk[8 * 128 * 32];        // [m][rq][i]      whh rows (q*32+dl), h-K

__device__ __forceinline__ float ftanh(float x) {
  float p = __builtin_exp2f(x * 2.885390081777927f);
  return 1.0f - 2.0f * __builtin_amdgcn_rcpf(p + 1.0f);
}
__device__ __forceinline__ float fsigm(float x) {
  float p = __builtin_exp2f(-x * 1.4426950408889634f);
  return __builtin_amdgcn_rcpf(1.0f + p);
}
__device__ __forceinline__ float dot4(float4 a, float4 b) {
  return a.x * b.x + a.y * b.y + a.z * b.z + a.w * b.w;
}
__device__ __forceinline__ float fd2(unsigned w, unsigned h, float acc) {
  h2 a = __builtin_bit_cast(h2, w), b = __builtin_bit_cast(h2, h);
#if __has_builtin(__builtin_amdgcn_fdot2)
  return __builtin_amdgcn_fdot2(a, b, acc, false);
#else
  return acc + (float)a.x * (float)b.x + (float)a.y * (float)b.y;
#endif
}
__device__ __forceinline__ float fd2x4u(uint4 w, uint4 h, float acc) {
  acc = fd2(w.x, h.x, acc);
  acc = fd2(w.y, h.y, acc);
  acc = fd2(w.z, h.z, acc);
  acc = fd2(w.w, h.w, acc);
  return acc;
}
__device__ __forceinline__ unsigned pk(float a, float b) {
  h2 h = {(_Float16)a, (_Float16)b};
  return __builtin_bit_cast(unsigned, h);
}
__device__ __forceinline__ void ast(unsigned* p, unsigned v) {
  __hip_atomic_store(p, v, __ATOMIC_RELAXED, __HIP_MEMORY_SCOPE_AGENT);
}
__device__ __forceinline__ unsigned ald(unsigned* p) {
  return __hip_atomic_load(p, __ATOMIC_RELAXED, __HIP_MEMORY_SCOPE_AGENT);
}
__device__ __forceinline__ float aldf(unsigned* p) {
  return __builtin_bit_cast(float, ald(p));
}

// state phys layout: logical uint4 L (0..63) of chain c -> c*68 + (L>>4)*17 + (L&15)
#define STPHYS(c, L) ((c) * 68 + ((L) >> 4) * 17 + ((L) & 15))

// ---------------- reset ----------------
__global__ void reset_kernel(float* out) {
  int t = threadIdx.x;
  if (t < 256) { g_sf[t] = 0u; g_stf[t] = 0u; }
  if (t < 512) out[t] = 0.f;
}

// ---------------- pack weights into member slices ----------------
__global__ __launch_bounds__(256) void pack_kernel(const float* __restrict__ w1,
                                                   const float* __restrict__ w_hh) {
  int idx = blockIdx.x * 256 + threadIdx.x;  // 49152 tasks
  const float* src;
  uint4* dst;
  if (idx < 16384) {                         // w1: m, e_loc, ku
    int m = idx >> 11, e_loc = (idx >> 6) & 31, ku = idx & 63;
    int e = m * 32 + e_loc;
    src = w1 + (size_t)e * 768 + 8 * ku;     // cols 0..511 = [W1h|W1c]
    dst = g_w1pk + idx;
  } else {                                   // whh: m, rq=q*32+dl, i
    int j = idx - 16384;
    int m = j >> 12, rq = (j >> 5) & 127, i = j & 31;
    int q = rq >> 5, dl = rq & 31;
    int R = q * 256 + m * 32 + dl;
    src = w_hh + (size_t)R * 256 + 8 * i;
    dst = g_whpk + j;
  }
  uint4 o;
  o.x = pk(src[0], src[1]); o.y = pk(src[2], src[3]);
  o.z = pk(src[4], src[5]); o.w = pk(src[6], src[7]);
  *dst = o;
}

// ---------------- eproj: b1 + W1e @ enc -> f16 pairs ----------------
__global__ __launch_bounds__(256) void eproj_kernel(const float* __restrict__ enc,
                                                    const float* __restrict__ w1,
                                                    const float* __restrict__ b1) {
  __shared__ __align__(16) float4 encs[16][64];
  __shared__ float accs[16][256];
  const int m0 = blockIdx.x * 16;
  const int tid = threadIdx.x;
  const float4* eg = (const float4*)(enc + (size_t)m0 * 256);
#pragma unroll
  for (int i = 0; i < 4; i++) {
    int idx = tid + 256 * i;
    encs[idx >> 6][idx & 63] = eg[idx];
  }
  __syncthreads();
  const int e = tid;
  float acc[16];
#pragma unroll
  for (int i = 0; i < 16; i++) acc[i] = 0.f;
  const float4* wrow = (const float4*)(w1 + e * 768 + 512);
  for (int k4 = 0; k4 < 64; k4++) {
    float4 wv = wrow[k4];
#pragma unroll
    for (int i = 0; i < 16; i++) acc[i] += dot4(wv, encs[i][k4]);
  }
  float bb = b1[e];
#pragma unroll
  for (int i = 0; i < 16; i++) accs[i][e] = acc[i] + bb;
  __syncthreads();
#pragma unroll
  for (int r = 0; r < 8; r++) {
    int idx = r * 256 + tid;
    int i = idx >> 7, jp = idx & 127;
    g_ep16[(size_t)(m0 + i) * 128 + jp] = pk(accs[i][2 * jp], accs[i][2 * jp + 1]);
  }
}

// ---------------- ENCFC / ENCFCF precompute ----------------
__global__ __launch_bounds__(256) void encfc_kernel(const float* __restrict__ enc,
                                                    const float* __restrict__ fc_w,
                                                    const float* __restrict__ fcf_w) {
  __shared__ __align__(16) float4 encs[16][64];
  const int m0 = blockIdx.x * 16;
  const int tid = threadIdx.x;
  const float4* eg = (const float4*)(enc + (size_t)m0 * 256);
#pragma unroll
  for (int i = 0; i < 4; i++) {
    int idx = tid + 256 * i;
    encs[idx >> 6][idx & 63] = eg[idx];
  }
  __syncthreads();
  if (tid < 128) {
    const int r = tid >> 3, o = tid & 7;
    const float* wr = (o < 4) ? (fc_w + o * 260) : (fcf_w + (o - 4) * 512 + 256);
    const float4* w4 = (const float4*)wr;
    float a = 0.f;
#pragma unroll 8
    for (int k = 0; k < 64; k++) a += dot4(w4[k], encs[r][k]);
    if (o < 4) ((float*)&g_encfc[m0 + r])[o] = a;
    else ((float*)&g_encfcf[m0 + r])[o - 4] = a;
  }
}

// -------- decoder: R15 structure at 1024 threads (16 waves/CU latency hiding) --------
__global__ __launch_bounds__(1024, 1) void decoder_kernel(
    const float* __restrict__ yhist, const float* __restrict__ w2,
    const float* __restrict__ w_ih, const float* __restrict__ b_ih,
    const float* __restrict__ b_hh,
    const float* __restrict__ fc_w, const float* __restrict__ fc_b,
    const float* __restrict__ fcf_w, const float* __restrict__ fcf_b,
    float* __restrict__ out) {
  __shared__ __align__(16) uint4 w1l[32 * 65];    // 33.3 KB [e_loc][ku] pad65
  __shared__ __align__(16) uint4 whl[128 * 33];   // 67.6 KB [rq][i] pad33
  __shared__ __align__(16) uint4 ep_t[4 * 257];   // 16.4 KB [u4][c*64+w] pad257
  __shared__ __align__(16) uint4 st4[4 * 68];     //  4.3 KB state, phys STPHYS
  __shared__ __align__(16) float4 encfc_l[256];
  __shared__ __align__(16) float4 yh_l[256];
  __shared__ __align__(16) float4 wihl[132];      // [q*33+dl]
  __shared__ float biasl[132];                    // [q*33+dl]
  __shared__ float ag_l[4 * 133];                 // [c*133 + q*32+dl]
  __shared__ float hcp_l[4 * 36];
  __shared__ float w2_l[32];
  __shared__ float scp_l[256];                    // own score partials
  __shared__ float sc_part[7 * 256];              // one region per partner wave
  __shared__ float cl[132];                       // [c*33 + dl]
  __shared__ float fcy_l[16];
  __shared__ float fcb_l[4];

  const int g = blockIdx.x, t = threadIdx.x;
  const int m = (g >> 3) & 7;
  const int gx = g - 8 * m;
  const int G = (g & 7) * 4 + (g >> 6);
  const int cbase = 4 * G;
  const int l = t & 63, wv = t >> 6;              // 16 waves
  const int e_loc = t >> 5, ks5 = t & 31;         // A1: 32 lanes per e-row
  const int row = t >> 3, kq3 = t & 7;            // A2: 8 lanes per gate row

  unsigned* st32 = (unsigned*)st4;

  // ---- LDS init ----
#pragma unroll
  for (int j = 0; j < 2; j++) {
    int f = t + 1024 * j;
    w1l[(f >> 6) * 65 + (f & 63)] = g_w1pk[m * 2048 + f];
  }
#pragma unroll
  for (int j = 0; j < 4; j++) {
    int f = t + 1024 * j;
    whl[(f >> 5) * 33 + (f & 31)] = g_whpk[m * 4096 + f];
  }
  {
    int f = t;
    int u = f >> 8, cw = f & 255, c = cw >> 6, w = cw & 63;
    ep_t[u * 257 + cw] =
        ((const uint4*)(g_ep16 + ((size_t)((cbase + c) * 64 + w)) * 128))[m * 4 + u];
  }
  if (t < 272) st4[t] = (uint4){0u, 0u, 0u, 0u};
  if (t < 256) {
    int c = t >> 6, w = t & 63;
    encfc_l[t] = g_encfc[(cbase + c) * 64 + w];
    yh_l[t] = ((const float4*)yhist)[(cbase + c) * 64 + w];
  }
  if (t < 128) {
    int q = t >> 5, dl = t & 31;
    int R = q * 256 + m * 32 + dl;
    wihl[q * 33 + dl] = *(const float4*)(w_ih + (size_t)R * 4);
    biasl[q * 33 + dl] = b_ih[R] + b_hh[R];
  }
  if (t < 132) cl[t] = 0.f;
  if (t < 32) w2_l[t] = w2[m * 32 + t];
  if (t < 16) fcy_l[t] = fc_w[(t >> 2) * 260 + 256 + (t & 3)];
  if (t < 4) fcb_l[t] = fc_b[t];
  __syncthreads();

  float attw = 0.f;
  for (int tstep = 0; tstep < Wn; tstep++) {
    const int tb = tstep & 1;
    const unsigned want = (unsigned)(tstep + 1);
    // ---- A1: hcp for own 32 e-rows, 4 chains; 32 lanes/e-row (2 uint4 each) ----
    {
      float a0 = 0.f, a1 = 0.f, a2 = 0.f, a3 = 0.f;
      const uint4* wrow = &w1l[e_loc * 65 + 2 * ks5];
#pragma unroll
      for (int j = 0; j < 2; j++) {
        uint4 wvv = wrow[j];
        int ku = 2 * ks5 + j;
        int ph = (ku >> 4) * 17 + (ku & 15);
        a0 = fd2x4u(wvv, st4[ph], a0);
        a1 = fd2x4u(wvv, st4[68 + ph], a1);
        a2 = fd2x4u(wvv, st4[136 + ph], a2);
        a3 = fd2x4u(wvv, st4[204 + ph], a3);
      }
#pragma unroll
      for (int dd = 1; dd < 32; dd <<= 1) {
        a0 += __shfl_xor(a0, dd, 64);
        a1 += __shfl_xor(a1, dd, 64);
        a2 += __shfl_xor(a2, dd, 64);
        a3 += __shfl_xor(a3, dd, 64);
      }
      if (ks5 == 0) {
        hcp_l[e_loc] = a0;
        hcp_l[36 + e_loc] = a1;
        hcp_l[72 + e_loc] = a2;
        hcp_l[108 + e_loc] = a3;
      }
    }
    __syncthreads();  // B1
    // ---- B: score partials; 4 lanes per (c,w) ----
    {
      const int cB = t >> 8, wB = (t >> 2) & 63, qB = t & 3;
      float s = 0.f;
      uint4 uu = ep_t[qB * 257 + cB * 64 + wB];
      unsigned um[4] = {uu.x, uu.y, uu.z, uu.w};
#pragma unroll
      for (int ui = 0; ui < 4; ui++) {
        int e0 = 2 * (4 * qB + ui);
        h2 aa = __builtin_bit_cast(h2, um[ui]);
        s += w2_l[e0] * ftanh((float)aa.x + hcp_l[cB * 36 + e0]);
        s += w2_l[e0 + 1] * ftanh((float)aa.y + hcp_l[cB * 36 + e0 + 1]);
      }
      s += __shfl_xor(s, 1, 64);
      s += __shfl_xor(s, 2, 64);
      if (qB == 0) scp_l[cB * 64 + wB] = s;
    }
    __syncthreads();  // B2
    // ---- post scores (wave 0) then everyone does A2; waves 1-7 gather 1 partner each ----
    if (wv == 0) {
      unsigned* dst = &g_scp[g][tb][4 * l];
      ast(dst + 0, __builtin_bit_cast(unsigned, scp_l[4 * l + 0]));
      ast(dst + 1, __builtin_bit_cast(unsigned, scp_l[4 * l + 1]));
      ast(dst + 2, __builtin_bit_cast(unsigned, scp_l[4 * l + 2]));
      ast(dst + 3, __builtin_bit_cast(unsigned, scp_l[4 * l + 3]));
      asm volatile("s_waitcnt vmcnt(0)" ::: "memory");
      if (l == 0) ast(&g_sf[g], want);
    }
    // ---- A2: gate h-dots; 8 lanes per row (4 uint4 each), 4 chains per read ----
    {
      float b0 = 0.f, b1 = 0.f, b2 = 0.f, b3 = 0.f;
      const uint4* wr = &whl[row * 33 + 4 * kq3];
#pragma unroll
      for (int j = 0; j < 4; j++) {
        uint4 wvv = wr[j];
        int i = 4 * kq3 + j;  // logical uint4 0..31 (h region)
        int ph = (i >> 4) * 17 + (i & 15);
        b0 = fd2x4u(wvv, st4[ph], b0);
        b1 = fd2x4u(wvv, st4[68 + ph], b1);
        b2 = fd2x4u(wvv, st4[136 + ph], b2);
        b3 = fd2x4u(wvv, st4[204 + ph], b3);
      }
#pragma unroll
      for (int dd = 1; dd < 8; dd <<= 1) {
        b0 += __shfl_xor(b0, dd, 64);
        b1 += __shfl_xor(b1, dd, 64);
        b2 += __shfl_xor(b2, dd, 64);
        b3 += __shfl_xor(b3, dd, 64);
      }
      if (kq3 == 0) {
        ag_l[row] = b0;
        ag_l[133 + row] = b1;
        ag_l[266 + row] = b2;
        ag_l[399 + row] = b3;
      }
    }
    // ---- gather scores: wave wv (1..7) handles partner (m+wv)&7 ----
    if (wv >= 1 && wv <= 7) {
      const int mo = (m + wv) & 7;
      if (l == 0) {
        unsigned* fp = &g_sf[gx + 8 * mo];
        while (ald(fp) < want) __builtin_amdgcn_s_sleep(1);
      }
      asm volatile("" ::: "memory");
      unsigned* sp = &g_scp[gx + 8 * mo][tb][4 * l];
      float* dst = &sc_part[(wv - 1) * 256 + 4 * l];
      dst[0] = aldf(sp + 0);
      dst[1] = aldf(sp + 1);
      dst[2] = aldf(sp + 2);
      dst[3] = aldf(sp + 3);
    }
    __syncthreads();  // B3
    // ---- C: softmax + ytilde (wave c = chain c) ----
    if (wv < 4) {
      const int c = wv;
      float sc = scp_l[c * 64 + l];
#pragma unroll
      for (int k = 0; k < 7; k++) sc += sc_part[k * 256 + c * 64 + l];
      float mm = sc;
#pragma unroll
      for (int dd = 32; dd; dd >>= 1) mm = fmaxf(mm, __shfl_xor(mm, dd, 64));
      float pr = __builtin_exp2f((sc - mm) * 1.4426950408889634f);
      float su = pr;
#pragma unroll
      for (int dd = 32; dd; dd >>= 1) su += __shfl_xor(su, dd, 64);
      attw = pr * __builtin_amdgcn_rcpf(su);
      float4 ef = encfc_l[c * 64 + l];
      float rx = attw * ef.x, ry = attw * ef.y, rz = attw * ef.z, rw = attw * ef.w;
#pragma unroll
      for (int dd = 32; dd; dd >>= 1) {
        rx += __shfl_xor(rx, dd, 64);
        ry += __shfl_xor(ry, dd, 64);
        rz += __shfl_xor(rz, dd, 64);
        rw += __shfl_xor(rw, dd, 64);
      }
      if (l == 0) {
        float4 yv = yh_l[c * 64 + tstep];
        float4 yt;
        yt.x = rx + fcb_l[0] + fcy_l[0] * yv.x + fcy_l[1] * yv.y + fcy_l[2] * yv.z + fcy_l[3] * yv.w;
        yt.y = ry + fcb_l[1] + fcy_l[4] * yv.x + fcy_l[5] * yv.y + fcy_l[6] * yv.z + fcy_l[7] * yv.w;
        yt.z = rz + fcb_l[2] + fcy_l[8] * yv.x + fcy_l[9] * yv.y + fcy_l[10] * yv.z + fcy_l[11] * yv.w;
        yt.w = rw + fcb_l[3] + fcy_l[12] * yv.x + fcy_l[13] * yv.y + fcy_l[14] * yv.z + fcy_l[15] * yv.w;
        *(float4*)&ag_l[c * 133 + 128] = yt;  // stash yt in ag_l tail (unused slots 128..131)
      }
    }
    __syncthreads();  // B4
    // ---- D: gates + LSTM + post state (wave 0) ; state gather (waves 1-7, 1 partner each) ----
    if (wv == 0) {
      const int c = l >> 4, pp = l & 15;
      const int d0 = 2 * pp, d1 = d0 + 1;
      float4 yt = *(const float4*)&ag_l[c * 133 + 128];
#define GV(q, d) (ag_l[c * 133 + (q) * 32 + (d)] + biasl[(q) * 33 + (d)] + dot4(wihl[(q) * 33 + (d)], yt))
      float i0 = fsigm(GV(0, d0)), f0 = fsigm(GV(1, d0));
      float G0 = ftanh(GV(2, d0)), o0 = fsigm(GV(3, d0));
      float i1 = fsigm(GV(0, d1)), f1 = fsigm(GV(1, d1));
      float G1 = ftanh(GV(2, d1)), o1 = fsigm(GV(3, d1));
#undef GV
      float cn0 = f0 * cl[c * 33 + d0] + i0 * G0;
      float cn1 = f1 * cl[c * 33 + d1] + i1 * G1;
      float hn0 = o0 * ftanh(cn0), hn1 = o1 * ftanh(cn1);
      cl[c * 33 + d0] = cn0; cl[c * 33 + d1] = cn1;
      unsigned hp = pk(hn0, hn1), cp = pk(cn0, cn1);
      {
        int Lh = 4 * m + (pp >> 2), Lc = 32 + 4 * m + (pp >> 2);
        st32[4 * STPHYS(c, Lh) + (pp & 3)] = hp;
        st32[4 * STPHYS(c, Lc) + (pp & 3)] = cp;
      }
      if (tstep < 63) {
        ast(&g_stp[g][tb][c * 32 + pp], hp);
        ast(&g_stp[g][tb][c * 32 + 16 + pp], cp);
        asm volatile("s_waitcnt vmcnt(0)" ::: "memory");
        if (l == 0) ast(&g_stf[g], want);
      }
    } else if (wv <= 7 && tstep < 63) {
      const int mo = (m + wv) & 7;
      if (l == 0) {
        unsigned* fp = &g_stf[gx + 8 * mo];
        while (ald(fp) < want) __builtin_amdgcn_s_sleep(1);
      }
      asm volatile("" ::: "memory");
      if (l < 32) {
        unsigned* sp = &g_stp[gx + 8 * mo][tb][4 * l];
#pragma unroll
        for (int k2 = 0; k2 < 4; k2++) {
          unsigned v = ald(sp + k2);
          int i = 4 * l + k2;
          int c = i >> 5, r = i & 31, pp = r & 15, isC = r >> 4;
          int L = isC * 32 + 4 * mo + (pp >> 2);
          st32[4 * STPHYS(c, L) + (pp & 3)] = v;
        }
      }
    }
    __syncthreads();  // B5
  }

  // ---- final: out[b,f] += fcf_h (own d-slice) + [m==0](attn.ENCFCF + fcf_b) ----
  if (wv < 4) {
    const int c = wv, b = cbase + c;
    const int pp = l & 15, f = l >> 4;
    int Lh = 4 * m + (pp >> 2);
    h2 hh = __builtin_bit_cast(h2, st32[4 * STPHYS(c, Lh) + (pp & 3)]);
    const int d0 = m * 32 + 2 * pp;
    float v = fcf_w[f * 512 + d0] * (float)hh.x + fcf_w[f * 512 + d0 + 1] * (float)hh.y;
#pragma unroll
    for (int dd = 1; dd < 16; dd <<= 1) v += __shfl_xor(v, dd, 64);
    if (pp == 0) atomicAdd(out + b * 4 + f, v);
    if (m == 0) {
      float4 fv = g_encfcf[b * 64 + l];
      float vx = attw * fv.x, vy = attw * fv.y, vz = attw * fv.z, vw = attw * fv.w;
#pragma unroll
      for (int dd = 32; dd; dd >>= 1) {
        vx += __shfl_xor(vx, dd, 64);
        vy += __shfl_xor(vy, dd, 64);
        vz += __shfl_xor(vz, dd, 64);
        vw += __shfl_xor(vw, dd, 64);
      }
      if (l == 0) {
        atomicAdd(out + b * 4 + 0, vx + fcf_b[0]);
        atomicAdd(out + b * 4 + 1, vy + fcf_b[1]);
        atomicAdd(out + b * 4 + 2, vz + fcf_b[2]);
        atomicAdd(out + b * 4 + 3, vw + fcf_b[3]);
      }
    }
  }
}

extern "C" void kernel_launch(void* const* d_in, const int* in_sizes, int n_in,
                              void* d_out, int out_size, void* d_ws, size_t ws_size,
                              hipStream_t stream) {
  (void)in_sizes; (void)n_in; (void)d_ws; (void)ws_size; (void)out_size;
  const float* enc   = (const float*)d_in[0];
  const float* yhist = (const float*)d_in[1];
  const float* w1    = (const float*)d_in[2];
  const float* b1    = (const float*)d_in[3];
  const float* w2    = (const float*)d_in[4];
  // d_in[5] = attn_b2: softmax-invariant -> unused
  const float* w_ih  = (const float*)d_in[6];
  const float* w_hh  = (const float*)d_in[7];
  const float* b_ih  = (const float*)d_in[8];
  const float* b_hh  = (const float*)d_in[9];
  const float* fc_w  = (const float*)d_in[10];
  const float* fc_b  = (const float*)d_in[11];
  const float* fcf_w = (const float*)d_in[12];
  const float* fcf_b = (const float*)d_in[13];
  float* out = (float*)d_out;

  reset_kernel<<<dim3(1), dim3(512), 0, stream>>>(out);
  pack_kernel<<<dim3(192), dim3(256), 0, stream>>>(w1, w_hh);
  eproj_kernel<<<dim3(512), dim3(256), 0, stream>>>(enc, w1, b1);
  encfc_kernel<<<dim3(512), dim3(256), 0, stream>>>(enc, fc_w, fcf_w);
  decoder_kernel<<<dim3(256), dim3(1024), 0, stream>>>(yhist, w2, w_ih, b_ih, b_hh,
                                                       fc_w, fc_b, fcf_w, fcf_b, out);
}

// Round 18
// 589.556 us; speedup vs baseline: 1.2775x; 1.1928x over previous
//
#include <hip/hip_runtime.h>

#define Bn 128
#define Wn 64

typedef _Float16 h2 __attribute__((ext_vector_type(2)));

// ---- device state ----
__device__ unsigned g_sf[256];                // score partials posted, value t+1
__device__ unsigned g_stf[256];               // state slice posted, value t+1
__device__ unsigned g_scp[256][2][256];       // [g][t&1][c*64+w] score partials (f32 bits)
__device__ unsigned g_stp[256][2][128];       // [g][t&1][c*32 + (h:0..15|c:16..31)] f16 pairs
__device__ unsigned g_ep16[Bn * Wn * 128];    // eproj f16 pairs [b][w][128]
__device__ float4 g_encfc[Bn * Wn];           // fc_w[:, :256] @ enc
__device__ float4 g_encfcf[Bn * Wn];          // fcf_w[:, 256:] @ enc
__device__ uint4 g_w1pk[8 * 32 * 64];         // [m][e_loc][ku]  w1 rows, full K (pairs)
__device__ uint4 g_whpk[8 * 128 * 32];        // [m][rq][i]      whh rows (q*32+dl), h-K

__device__ __forceinline__ float ftanh(float x) {
  float p = __builtin_exp2f(x * 2.885390081777927f);
  return 1.0f - 2.0f * __builtin_amdgcn_rcpf(p + 1.0f);
}
__device__ __forceinline__ float fsigm(float x) {
  float p = __builtin_exp2f(-x * 1.4426950408889634f);
  return __builtin_amdgcn_rcpf(1.0f + p);
}
__device__ __forceinline__ float dot4(float4 a, float4 b) {
  return a.x * b.x + a.y * b.y + a.z * b.z + a.w * b.w;
}
__device__ __forceinline__ float fd2(unsigned w, unsigned h, float acc) {
  h2 a = __builtin_bit_cast(h2, w), b = __builtin_bit_cast(h2, h);
#if __has_builtin(__builtin_amdgcn_fdot2)
  return __builtin_amdgcn_fdot2(a, b, acc, false);
#else
  return acc + (float)a.x * (float)b.x + (float)a.y * (float)b.y;
#endif
}
__device__ __forceinline__ float fd2x4u(uint4 w, uint4 h, float acc) {
  acc = fd2(w.x, h.x, acc);
  acc = fd2(w.y, h.y, acc);
  acc = fd2(w.z, h.z, acc);
  acc = fd2(w.w, h.w, acc);
  return acc;
}
__device__ __forceinline__ unsigned pk(float a, float b) {
  h2 h = {(_Float16)a, (_Float16)b};
  return __builtin_bit_cast(unsigned, h);
}
__device__ __forceinline__ void ast(unsigned* p, unsigned v) {
  __hip_atomic_store(p, v, __ATOMIC_RELAXED, __HIP_MEMORY_SCOPE_AGENT);
}
__device__ __forceinline__ unsigned ald(unsigned* p) {
  return __hip_atomic_load(p, __ATOMIC_RELAXED, __HIP_MEMORY_SCOPE_AGENT);
}
__device__ __forceinline__ float aldf(unsigned* p) {
  return __builtin_bit_cast(float, ald(p));
}

// state phys layout: logical uint4 L (0..63) of chain c -> c*68 + (L>>4)*17 + (L&15)
#define STPHYS(c, L) ((c) * 68 + ((L) >> 4) * 17 + ((L) & 15))

// ---------------- reset ----------------
__global__ void reset_kernel(float* out) {
  int t = threadIdx.x;
  if (t < 256) { g_sf[t] = 0u; g_stf[t] = 0u; }
  if (t < 512) out[t] = 0.f;
}

// ---------------- pack weights into member slices ----------------
__global__ __launch_bounds__(256) void pack_kernel(const float* __restrict__ w1,
                                                   const float* __restrict__ w_hh) {
  int idx = blockIdx.x * 256 + threadIdx.x;  // 49152 tasks
  const float* src;
  uint4* dst;
  if (idx < 16384) {                         // w1: m, e_loc, ku
    int m = idx >> 11, e_loc = (idx >> 6) & 31, ku = idx & 63;
    int e = m * 32 + e_loc;
    src = w1 + (size_t)e * 768 + 8 * ku;     // cols 0..511 = [W1h|W1c]
    dst = g_w1pk + idx;
  } else {                                   // whh: m, rq=q*32+dl, i
    int j = idx - 16384;
    int m = j >> 12, rq = (j >> 5) & 127, i = j & 31;
    int q = rq >> 5, dl = rq & 31;
    int R = q * 256 + m * 32 + dl;
    src = w_hh + (size_t)R * 256 + 8 * i;
    dst = g_whpk + j;
  }
  uint4 o;
  o.x = pk(src[0], src[1]); o.y = pk(src[2], src[3]);
  o.z = pk(src[4], src[5]); o.w = pk(src[6], src[7]);
  *dst = o;
}

// ---------------- eproj: b1 + W1e @ enc -> f16 pairs ----------------
__global__ __launch_bounds__(256) void eproj_kernel(const float* __restrict__ enc,
                                                    const float* __restrict__ w1,
                                                    const float* __restrict__ b1) {
  __shared__ __align__(16) float4 encs[16][64];
  __shared__ float accs[16][256];
  const int m0 = blockIdx.x * 16;
  const int tid = threadIdx.x;
  const float4* eg = (const float4*)(enc + (size_t)m0 * 256);
#pragma unroll
  for (int i = 0; i < 4; i++) {
    int idx = tid + 256 * i;
    encs[idx >> 6][idx & 63] = eg[idx];
  }
  __syncthreads();
  const int e = tid;
  float acc[16];
#pragma unroll
  for (int i = 0; i < 16; i++) acc[i] = 0.f;
  const float4* wrow = (const float4*)(w1 + e * 768 + 512);
  for (int k4 = 0; k4 < 64; k4++) {
    float4 wv = wrow[k4];
#pragma unroll
    for (int i = 0; i < 16; i++) acc[i] += dot4(wv, encs[i][k4]);
  }
  float bb = b1[e];
#pragma unroll
  for (int i = 0; i < 16; i++) accs[i][e] = acc[i] + bb;
  __syncthreads();
#pragma unroll
  for (int r = 0; r < 8; r++) {
    int idx = r * 256 + tid;
    int i = idx >> 7, jp = idx & 127;
    g_ep16[(size_t)(m0 + i) * 128 + jp] = pk(accs[i][2 * jp], accs[i][2 * jp + 1]);
  }
}

// ---------------- ENCFC / ENCFCF precompute ----------------
__global__ __launch_bounds__(256) void encfc_kernel(const float* __restrict__ enc,
                                                    const float* __restrict__ fc_w,
                                                    const float* __restrict__ fcf_w) {
  __shared__ __align__(16) float4 encs[16][64];
  const int m0 = blockIdx.x * 16;
  const int tid = threadIdx.x;
  const float4* eg = (const float4*)(enc + (size_t)m0 * 256);
#pragma unroll
  for (int i = 0; i < 4; i++) {
    int idx = tid + 256 * i;
    encs[idx >> 6][idx & 63] = eg[idx];
  }
  __syncthreads();
  if (tid < 128) {
    const int r = tid >> 3, o = tid & 7;
    const float* wr = (o < 4) ? (fc_w + o * 260) : (fcf_w + (o - 4) * 512 + 256);
    const float4* w4 = (const float4*)wr;
    float a = 0.f;
#pragma unroll 8
    for (int k = 0; k < 64; k++) a += dot4(w4[k], encs[r][k]);
    if (o < 4) ((float*)&g_encfc[m0 + r])[o] = a;
    else ((float*)&g_encfcf[m0 + r])[o - 4] = a;
  }
}

// -------- decoder: 8-CU LDS-parked group; R13 structure + parallel 1-partner-per-wave gathers --------
__global__ __launch_bounds__(512, 1) void decoder_kernel(
    const float* __restrict__ yhist, const float* __restrict__ w2,
    const float* __restrict__ w_ih, const float* __restrict__ b_ih,
    const float* __restrict__ b_hh,
    const float* __restrict__ fc_w, const float* __restrict__ fc_b,
    const float* __restrict__ fcf_w, const float* __restrict__ fcf_b,
    float* __restrict__ out) {
  __shared__ __align__(16) uint4 w1l[32 * 65];    // 33.3 KB [e_loc][ku] pad65
  __shared__ __align__(16) uint4 whl[128 * 33];   // 67.6 KB [rq][i] pad33
  __shared__ __align__(16) uint4 ep_t[4 * 257];   // 16.4 KB [u4][c*64+w] pad257
  __shared__ __align__(16) uint4 st4[4 * 68];     //  4.3 KB state, phys STPHYS
  __shared__ __align__(16) float4 encfc_l[256];
  __shared__ __align__(16) float4 yh_l[256];
  __shared__ __align__(16) float4 wihl[132];      // [q*33+dl]
  __shared__ float biasl[132];                    // [q*33+dl]
  __shared__ float ag_l[4 * 133];                 // [c*133 + q*32+dl]
  __shared__ float hcp_l[4 * 36];
  __shared__ float w2_l[32];
  __shared__ float scp_l[256];                    // own score partials
  __shared__ float sc_part[7 * 256];              // one region per partner wave
  __shared__ float cl[132];                       // [c*33 + dl]
  __shared__ __align__(16) float4 ytl[4];
  __shared__ float fcy_l[16];
  __shared__ float fcb_l[4];

  const int g = blockIdx.x, t = threadIdx.x;
  const int m = (g >> 3) & 7;
  const int gx = g - 8 * m;
  const int G = (g & 7) * 4 + (g >> 6);
  const int cbase = 4 * G;
  const int l = t & 63, wv = t >> 6;
  const int e_loc = t >> 4, ks = t & 15;   // A1 mapping
  const int row = t >> 2, kq2 = t & 3;     // A2 mapping

  unsigned* st32 = (unsigned*)st4;

  // ---- LDS init ----
#pragma unroll
  for (int j = 0; j < 4; j++) {
    int f = t + 512 * j;
    w1l[(f >> 6) * 65 + (f & 63)] = g_w1pk[m * 2048 + f];
  }
#pragma unroll
  for (int j = 0; j < 8; j++) {
    int f = t + 512 * j;
    whl[(f >> 5) * 33 + (f & 31)] = g_whpk[m * 4096 + f];
  }
#pragma unroll
  for (int j = 0; j < 2; j++) {
    int f = t + 512 * j;
    int u = f >> 8, cw = f & 255, c = cw >> 6, w = cw & 63;
    ep_t[u * 257 + cw] =
        ((const uint4*)(g_ep16 + ((size_t)((cbase + c) * 64 + w)) * 128))[m * 4 + u];
  }
  if (t < 272) st4[t] = (uint4){0u, 0u, 0u, 0u};
  if (t < 256) {
    int c = t >> 6, w = t & 63;
    encfc_l[t] = g_encfc[(cbase + c) * 64 + w];
    yh_l[t] = ((const float4*)yhist)[(cbase + c) * 64 + w];
  }
  if (t < 128) {
    int q = t >> 5, dl = t & 31;
    int R = q * 256 + m * 32 + dl;
    wihl[q * 33 + dl] = *(const float4*)(w_ih + (size_t)R * 4);
    biasl[q * 33 + dl] = b_ih[R] + b_hh[R];
  }
  if (t < 132) cl[t] = 0.f;
  if (t < 32) w2_l[t] = w2[m * 32 + t];
  if (t < 16) fcy_l[t] = fc_w[(t >> 2) * 260 + 256 + (t & 3)];
  if (t < 4) fcb_l[t] = fc_b[t];
  __syncthreads();

  float attw = 0.f;
  for (int tstep = 0; tstep < Wn; tstep++) {
    const int tb = tstep & 1;
    const unsigned want = (unsigned)(tstep + 1);
    // ---- A1: hcp for own 32 e-rows, 4 chains, full K=512 ----
    {
      float a0 = 0.f, a1 = 0.f, a2 = 0.f, a3 = 0.f;
      const uint4* wrow = &w1l[e_loc * 65 + 4 * ks];
#pragma unroll
      for (int j = 0; j < 4; j++) {
        uint4 wvv = wrow[j];
        int ku = 4 * ks + j;
        int ph = (ku >> 4) * 17 + (ku & 15);
        a0 = fd2x4u(wvv, st4[ph], a0);
        a1 = fd2x4u(wvv, st4[68 + ph], a1);
        a2 = fd2x4u(wvv, st4[136 + ph], a2);
        a3 = fd2x4u(wvv, st4[204 + ph], a3);
      }
#pragma unroll
      for (int dd = 1; dd < 16; dd <<= 1) {
        a0 += __shfl_xor(a0, dd, 64);
        a1 += __shfl_xor(a1, dd, 64);
        a2 += __shfl_xor(a2, dd, 64);
        a3 += __shfl_xor(a3, dd, 64);
      }
      if (ks == 0) {
        hcp_l[e_loc] = a0;
        hcp_l[36 + e_loc] = a1;
        hcp_l[72 + e_loc] = a2;
        hcp_l[108 + e_loc] = a3;
      }
    }
    __syncthreads();  // B1
    // ---- B: score partials over own 32 e's ----
    {
      const int cB = t >> 7, wB = (t & 127) >> 1, halfB = t & 1;
      float s = 0.f;
#pragma unroll
      for (int j = 0; j < 2; j++) {
        int u = 2 * halfB + j;
        uint4 uu = ep_t[u * 257 + cB * 64 + wB];
        unsigned um[4] = {uu.x, uu.y, uu.z, uu.w};
#pragma unroll
        for (int ui = 0; ui < 4; ui++) {
          int e0 = 2 * (4 * u + ui);
          h2 aa = __builtin_bit_cast(h2, um[ui]);
          s += w2_l[e0] * ftanh((float)aa.x + hcp_l[cB * 36 + e0]);
          s += w2_l[e0 + 1] * ftanh((float)aa.y + hcp_l[cB * 36 + e0 + 1]);
        }
      }
      s += __shfl_xor(s, 1, 64);
      if (halfB == 0) scp_l[cB * 64 + wB] = s;
    }
    __syncthreads();  // B2
    // ---- post scores (wave 0) then everyone does A2; waves 1-7 gather 1 partner each ----
    if (wv == 0) {
      unsigned* dst = &g_scp[g][tb][4 * l];
      ast(dst + 0, __builtin_bit_cast(unsigned, scp_l[4 * l + 0]));
      ast(dst + 1, __builtin_bit_cast(unsigned, scp_l[4 * l + 1]));
      ast(dst + 2, __builtin_bit_cast(unsigned, scp_l[4 * l + 2]));
      ast(dst + 3, __builtin_bit_cast(unsigned, scp_l[4 * l + 3]));
      asm volatile("s_waitcnt vmcnt(0)" ::: "memory");
      if (l == 0) ast(&g_sf[g], want);
    }
    // ---- A2: gate h-dots; thread=(row,kq2) computes 4 chains from ONE whl read ----
    {
      float b0 = 0.f, b1 = 0.f, b2 = 0.f, b3 = 0.f;
      const uint4* wr = &whl[row * 33 + 8 * kq2];
#pragma unroll
      for (int j = 0; j < 8; j++) {
        uint4 wvv = wr[j];
        int i = 8 * kq2 + j;  // logical uint4 0..31 (h region)
        int ph = (i >> 4) * 17 + (i & 15);
        b0 = fd2x4u(wvv, st4[ph], b0);
        b1 = fd2x4u(wvv, st4[68 + ph], b1);
        b2 = fd2x4u(wvv, st4[136 + ph], b2);
        b3 = fd2x4u(wvv, st4[204 + ph], b3);
      }
#pragma unroll
      for (int dd = 1; dd < 4; dd <<= 1) {
        b0 += __shfl_xor(b0, dd, 64);
        b1 += __shfl_xor(b1, dd, 64);
        b2 += __shfl_xor(b2, dd, 64);
        b3 += __shfl_xor(b3, dd, 64);
      }
      if (kq2 == 0) {
        ag_l[row] = b0;
        ag_l[133 + row] = b1;
        ag_l[266 + row] = b2;
        ag_l[399 + row] = b3;
      }
    }
    // ---- gather scores: wave wv (1..7) handles partner (m+wv)&7 ----
    if (wv >= 1) {
      const int mo = (m + wv) & 7;
      if (l == 0) {
        unsigned* fp = &g_sf[gx + 8 * mo];
        while (ald(fp) < want) __builtin_amdgcn_s_sleep(1);
      }
      asm volatile("" ::: "memory");
      unsigned* sp = &g_scp[gx + 8 * mo][tb][4 * l];
      float* dst = &sc_part[(wv - 1) * 256 + 4 * l];
      dst[0] = aldf(sp + 0);
      dst[1] = aldf(sp + 1);
      dst[2] = aldf(sp + 2);
      dst[3] = aldf(sp + 3);
    }
    __syncthreads();  // B3
    // ---- C: softmax + ytilde (wave c = chain c) ----
    if (wv < 4) {
      const int c = wv;
      float sc = scp_l[c * 64 + l];
#pragma unroll
      for (int k = 0; k < 7; k++) sc += sc_part[k * 256 + c * 64 + l];
      float mm = sc;
#pragma unroll
      for (int dd = 32; dd; dd >>= 1) mm = fmaxf(mm, __shfl_xor(mm, dd, 64));
      float pr = __builtin_exp2f((sc - mm) * 1.4426950408889634f);
      float su = pr;
#pragma unroll
      for (int dd = 32; dd; dd >>= 1) su += __shfl_xor(su, dd, 64);
      attw = pr * __builtin_amdgcn_rcpf(su);
      float4 ef = encfc_l[c * 64 + l];
      float rx = attw * ef.x, ry = attw * ef.y, rz = attw * ef.z, rw = attw * ef.w;
#pragma unroll
      for (int dd = 32; dd; dd >>= 1) {
        rx += __shfl_xor(rx, dd, 64);
        ry += __shfl_xor(ry, dd, 64);
        rz += __shfl_xor(rz, dd, 64);
        rw += __shfl_xor(rw, dd, 64);
      }
      if (l == 0) {
        float4 yv = yh_l[c * 64 + tstep];
        float4 yt;
        yt.x = rx + fcb_l[0] + fcy_l[0] * yv.x + fcy_l[1] * yv.y + fcy_l[2] * yv.z + fcy_l[3] * yv.w;
        yt.y = ry + fcb_l[1] + fcy_l[4] * yv.x + fcy_l[5] * yv.y + fcy_l[6] * yv.z + fcy_l[7] * yv.w;
        yt.z = rz + fcb_l[2] + fcy_l[8] * yv.x + fcy_l[9] * yv.y + fcy_l[10] * yv.z + fcy_l[11] * yv.w;
        yt.w = rw + fcb_l[3] + fcy_l[12] * yv.x + fcy_l[13] * yv.y + fcy_l[14] * yv.z + fcy_l[15] * yv.w;
        ytl[c] = yt;
      }
    }
    __syncthreads();  // B4
    // ---- D: gates + LSTM + post state (wave 0) ; state gather (waves 1-7, 1 partner each) ----
    if (wv == 0) {
      const int c = l >> 4, pp = l & 15;
      const int d0 = 2 * pp, d1 = d0 + 1;
      float4 yt = ytl[c];
#define GV(q, d) (ag_l[c * 133 + (q) * 32 + (d)] + biasl[(q) * 33 + (d)] + dot4(wihl[(q) * 33 + (d)], yt))
      float i0 = fsigm(GV(0, d0)), f0 = fsigm(GV(1, d0));
      float G0 = ftanh(GV(2, d0)), o0 = fsigm(GV(3, d0));
      float i1 = fsigm(GV(0, d1)), f1 = fsigm(GV(1, d1));
      float G1 = ftanh(GV(2, d1)), o1 = fsigm(GV(3, d1));
#undef GV
      float cn0 = f0 * cl[c * 33 + d0] + i0 * G0;
      float cn1 = f1 * cl[c * 33 + d1] + i1 * G1;
      float hn0 = o0 * ftanh(cn0), hn1 = o1 * ftanh(cn1);
      cl[c * 33 + d0] = cn0; cl[c * 33 + d1] = cn1;
      unsigned hp = pk(hn0, hn1), cp = pk(cn0, cn1);
      {
        int Lh = 4 * m + (pp >> 2), Lc = 32 + 4 * m + (pp >> 2);
        st32[4 * STPHYS(c, Lh) + (pp & 3)] = hp;
        st32[4 * STPHYS(c, Lc) + (pp & 3)] = cp;
      }
      if (tstep < 63) {
        ast(&g_stp[g][tb][c * 32 + pp], hp);
        ast(&g_stp[g][tb][c * 32 + 16 + pp], cp);
        asm volatile("s_waitcnt vmcnt(0)" ::: "memory");
        if (l == 0) ast(&g_stf[g], want);
      }
    } else if (tstep < 63) {
      const int mo = (m + wv) & 7;
      if (l == 0) {
        unsigned* fp = &g_stf[gx + 8 * mo];
        while (ald(fp) < want) __builtin_amdgcn_s_sleep(1);
      }
      asm volatile("" ::: "memory");
      if (l < 32) {
        unsigned* sp = &g_stp[gx + 8 * mo][tb][4 * l];
#pragma unroll
        for (int k2 = 0; k2 < 4; k2++) {
          unsigned v = ald(sp + k2);
          int i = 4 * l + k2;
          int c = i >> 5, r = i & 31, pp = r & 15, isC = r >> 4;
          int L = isC * 32 + 4 * mo + (pp >> 2);
          st32[4 * STPHYS(c, L) + (pp & 3)] = v;
        }
      }
    }
    __syncthreads();  // B5
  }

  // ---- final: out[b,f] += fcf_h (own d-slice) + [m==0](attn.ENCFCF + fcf_b) ----
  if (wv < 4) {
    const int c = wv, b = cbase + c;
    const int pp = l & 15, f = l >> 4;
    int Lh = 4 * m + (pp >> 2);
    h2 hh = __builtin_bit_cast(h2, st32[4 * STPHYS(c, Lh) + (pp & 3)]);
    const int d0 = m * 32 + 2 * pp;
    float v = fcf_w[f * 512 + d0] * (float)hh.x + fcf_w[f * 512 + d0 + 1] * (float)hh.y;
#pragma unroll
    for (int dd = 1; dd < 16; dd <<= 1) v += __shfl_xor(v, dd, 64);
    if (pp == 0) atomicAdd(out + b * 4 + f, v);
    if (m == 0) {
      float4 fv = g_encfcf[b * 64 + l];
      float vx = attw * fv.x, vy = attw * fv.y, vz = attw * fv.z, vw = attw * fv.w;
#pragma unroll
      for (int dd = 32; dd; dd >>= 1) {
        vx += __shfl_xor(vx, dd, 64);
        vy += __shfl_xor(vy, dd, 64);
        vz += __shfl_xor(vz, dd, 64);
        vw += __shfl_xor(vw, dd, 64);
      }
      if (l == 0) {
        atomicAdd(out + b * 4 + 0, vx + fcf_b[0]);
        atomicAdd(out + b * 4 + 1, vy + fcf_b[1]);
        atomicAdd(out + b * 4 + 2, vz + fcf_b[2]);
        atomicAdd(out + b * 4 + 3, vw + fcf_b[3]);
      }
    }
  }
}

extern "C" void kernel_launch(void* const* d_in, const int* in_sizes, int n_in,
                              void* d_out, int out_size, void* d_ws, size_t ws_size,
                              hipStream_t stream) {
  (void)in_sizes; (void)n_in; (void)d_ws; (void)ws_size; (void)out_size;
  const float* enc   = (const float*)d_in[0];
  const float* yhist = (const float*)d_in[1];
  const float* w1    = (const float*)d_in[2];
  const float* b1    = (const float*)d_in[3];
  const float* w2    = (const float*)d_in[4];
  // d_in[5] = attn_b2: softmax-invariant -> unused
  const float* w_ih  = (const float*)d_in[6];
  const float* w_hh  = (const float*)d_in[7];
  const float* b_ih  = (const float*)d_in[8];
  const float* b_hh  = (const float*)d_in[9];
  const float* fc_w  = (const float*)d_in[10];
  const float* fc_b  = (const float*)d_in[11];
  const float* fcf_w = (const float*)d_in[12];
  const float* fcf_b = (const float*)d_in[13];
  float* out = (float*)d_out;

  reset_kernel<<<dim3(1), dim3(512), 0, stream>>>(out);
  pack_kernel<<<dim3(192), dim3(256), 0, stream>>>(w1, w_hh);
  eproj_kernel<<<dim3(512), dim3(256), 0, stream>>>(enc, w1, b1);
  encfc_kernel<<<dim3(512), dim3(256), 0, stream>>>(enc, fc_w, fcf_w);
  decoder_kernel<<<dim3(256), dim3(512), 0, stream>>>(yhist, w2, w_ih, b_ih, b_hh,
                                                      fc_w, fc_b, fcf_w, fcf_b, out);
}